// Round 2
// baseline (1225.818 us; speedup 1.0000x reference)
//
#include <hip/hip_runtime.h>
#include <hip/hip_bf16.h>

#define T_TOKENS 4096
#define D_MODEL  1024
#define N_EXP    16
#define D_FF     1024
#define D_FF_SH  2048

typedef __attribute__((ext_vector_type(8))) short short8;
typedef __attribute__((ext_vector_type(4))) float float4v;

__device__ __forceinline__ short f2bf(float f) {
    union { float f; unsigned u; } c; c.f = f;
    unsigned u = c.u + 0x7fffu + ((c.u >> 16) & 1u);
    return (short)(u >> 16);
}

// ---------------------------------------------------------------- convert
__global__ __launch_bounds__(256) void convert_kernel(const float* __restrict__ src,
                                                      short* __restrict__ dst, int n) {
    int i = (blockIdx.x * 256 + threadIdx.x) * 8;
    if (i >= n) return;
    float4 a = *(const float4*)(src + i);
    float4 b = *(const float4*)(src + i + 4);
    union { short s[8]; int4 v; } p;
    p.s[0] = f2bf(a.x); p.s[1] = f2bf(a.y); p.s[2] = f2bf(a.z); p.s[3] = f2bf(a.w);
    p.s[4] = f2bf(b.x); p.s[5] = f2bf(b.y); p.s[6] = f2bf(b.z); p.s[7] = f2bf(b.w);
    *(int4*)(dst + i) = p.v;
}

// ---------------------------------------------------------------- router (fp32 exact)
__global__ __launch_bounds__(256) void router_kernel(
    const float* __restrict__ x, const float* __restrict__ gw, const float* __restrict__ sgw,
    short* __restrict__ xb, int* __restrict__ topk_id, float* __restrict__ topk_w,
    float* __restrict__ gate, int* __restrict__ counts) {
    int wave = threadIdx.x >> 6, lane = threadIdx.x & 63;
    int t = blockIdx.x * 4 + wave;
    const float* xt = x + (size_t)t * D_MODEL;
    float acc[17];
#pragma unroll
    for (int e = 0; e < 17; e++) acc[e] = 0.f;
#pragma unroll
    for (int i = 0; i < 16; i++) {
        int d = lane + i * 64;
        float xv = xt[d];
        xb[(size_t)t * D_MODEL + d] = f2bf(xv);
#pragma unroll
        for (int e = 0; e < 16; e++) acc[e] += xv * gw[e * D_MODEL + d];
        acc[16] += xv * sgw[d];
    }
#pragma unroll
    for (int e = 0; e < 17; e++)
        for (int off = 32; off; off >>= 1) acc[e] += __shfl_xor(acc[e], off);
    if (lane == 0) {
        float v1 = -1e30f, v2 = -1e30f; int i1 = 0, i2 = 0;
#pragma unroll
        for (int e = 0; e < 16; e++) {
            float v = acc[e];
            if (v > v1) { v2 = v1; i2 = i1; v1 = v; i1 = e; }
            else if (v > v2) { v2 = v; i2 = e; }
        }
        float e2 = expf(v2 - v1);
        float s = 1.f + e2;
        topk_id[t * 2] = i1; topk_id[t * 2 + 1] = i2;
        topk_w[t * 2] = 1.f / s; topk_w[t * 2 + 1] = e2 / s;
        gate[t] = 1.f / (1.f + expf(-acc[16]));
        atomicAdd(&counts[i1], 1); atomicAdd(&counts[i2], 1);
    }
}

// ---------------------------------------------------------------- offsets / scatter
__global__ void offsets_kernel(const int* __restrict__ counts, int* __restrict__ offsets,
                               int* __restrict__ cursor) {
    if (threadIdx.x == 0) {
        int off = 0;
        for (int e = 0; e < N_EXP; e++) { offsets[e] = off; cursor[e] = off; off += counts[e]; }
    }
}

__global__ __launch_bounds__(256) void scatter_kernel(
    const int* __restrict__ topk_id, const float* __restrict__ topk_w,
    int* __restrict__ cursor, int* __restrict__ tok_list, float* __restrict__ tok_w) {
    int t = blockIdx.x * 256 + threadIdx.x;
#pragma unroll
    for (int k = 0; k < 2; k++) {
        int e = topk_id[t * 2 + k];
        int pos = atomicAdd(&cursor[e], 1);
        tok_list[pos] = t;
        tok_w[pos] = topk_w[t * 2 + k];
    }
}

// ---------------------------------------------------------------- GEMM1: h = silu(x@Wg^T) * (x@Wu^T)
// A rows gathered via tok_list (or identity if counts==nullptr / shared expert).
__global__ __launch_bounds__(256, 2) void gemm1_kernel(
    const short* __restrict__ A,  // x bf16 [T][1024]
    const short* __restrict__ W,  // bf16 [E][2*dff][1024] (or [2*dff][1024] shared)
    short* __restrict__ H,        // [slots][dff]
    const int* __restrict__ tok_list, const int* __restrict__ offsets,
    const int* __restrict__ counts, int dff) {
    const int K = D_MODEL;
    int count, base;
    const int* idx;
    const short* Wg;
    if (counts) {
        int e = blockIdx.z;
        count = counts[e]; base = offsets[e];
        idx = tok_list + base;
        Wg = W + (size_t)e * 2 * dff * K;
    } else { count = T_TOKENS; base = 0; idx = nullptr; Wg = W; }
    int row0 = blockIdx.x * 128;
    if (row0 >= count) return;
    int col0 = blockIdx.y * 128;
    const short* Wu = Wg + (size_t)dff * K;
    short* Hout = H + (size_t)base * dff;

    __shared__ short As[128 * 40];
    __shared__ short Bg[128 * 40];
    __shared__ short Bu[128 * 40];

    int tid = threadIdx.x;
    int wave = tid >> 6, lane = tid & 63;
    int wm = (wave & 1) * 64, wn = (wave >> 1) * 64;
    int fr = lane & 15, fk = (lane >> 4) * 8;

    float4v accg[4][4], accu[4][4];
#pragma unroll
    for (int i = 0; i < 4; i++)
#pragma unroll
        for (int j = 0; j < 4; j++) {
            accg[i][j] = (float4v)0.f; accu[i][j] = (float4v)0.f;
        }

    int r0 = tid >> 2;            // staging row 0..63 (and +64)
    int kq = (tid & 3) * 8;       // k element offset (16B chunks)
    const short* arow[2]; const short* bgrow[2]; const short* burow[2];
#pragma unroll
    for (int ii = 0; ii < 2; ii++) {
        int r = r0 + ii * 64;     // r ALREADY includes ii*64
        int rr = min(row0 + r, count - 1);
        int g = idx ? idx[rr] : rr;
        arow[ii] = A + (size_t)g * K;
        bgrow[ii] = Wg + (size_t)(col0 + r) * K;
        burow[ii] = Wu + (size_t)(col0 + r) * K;
    }

    for (int k0 = 0; k0 < K; k0 += 32) {
#pragma unroll
        for (int ii = 0; ii < 2; ii++) {
            int r = r0 + ii * 64;
            *(int4*)&As[r * 40 + kq] = *(const int4*)(arow[ii] + k0 + kq);
            *(int4*)&Bg[r * 40 + kq] = *(const int4*)(bgrow[ii] + k0 + kq);
            *(int4*)&Bu[r * 40 + kq] = *(const int4*)(burow[ii] + k0 + kq);
        }
        __syncthreads();
        short8 a[4], bg[4], bu[4];
#pragma unroll
        for (int i = 0; i < 4; i++) a[i] = *(const short8*)&As[(wm + i * 16 + fr) * 40 + fk];
#pragma unroll
        for (int j = 0; j < 4; j++) {
            bg[j] = *(const short8*)&Bg[(wn + j * 16 + fr) * 40 + fk];
            bu[j] = *(const short8*)&Bu[(wn + j * 16 + fr) * 40 + fk];
        }
#pragma unroll
        for (int i = 0; i < 4; i++)
#pragma unroll
            for (int j = 0; j < 4; j++) {
                accg[i][j] = __builtin_amdgcn_mfma_f32_16x16x32_bf16(a[i], bg[j], accg[i][j], 0, 0, 0);
                accu[i][j] = __builtin_amdgcn_mfma_f32_16x16x32_bf16(a[i], bu[j], accu[i][j], 0, 0, 0);
            }
        __syncthreads();
    }

    int erow = (lane >> 4) * 4;
    int ecol = lane & 15;
#pragma unroll
    for (int i = 0; i < 4; i++)
#pragma unroll
        for (int j = 0; j < 4; j++)
#pragma unroll
            for (int r = 0; r < 4; r++) {
                int row = wm + i * 16 + erow + r;
                if (row0 + row < count) {
                    float g = accg[i][j][r], u = accu[i][j][r];
                    float h = g / (1.f + expf(-g)) * u;
                    Hout[(size_t)(row0 + row) * dff + col0 + wn + j * 16 + ecol] = f2bf(h);
                }
            }
}

// ---------------------------------------------------------------- GEMM2: out += w * (h @ Wd^T)
__global__ __launch_bounds__(256, 2) void gemm2_kernel(
    const short* __restrict__ H, int K,   // lda = K (1024 expert / 2048 shared)
    const short* __restrict__ Wd,         // bf16 [E][1024][K] or [1024][K]
    float* __restrict__ out,
    const int* __restrict__ tok_list, const float* __restrict__ tok_w,
    const int* __restrict__ offsets, const int* __restrict__ counts,
    const float* __restrict__ gate) {
    int count, base;
    const short* B;
    if (counts) {
        int e = blockIdx.z;
        count = counts[e]; base = offsets[e];
        B = Wd + (size_t)e * D_MODEL * K;
    } else { count = T_TOKENS; base = 0; B = Wd; }
    int row0 = blockIdx.x * 128;
    if (row0 >= count) return;
    int col0 = blockIdx.y * 128;
    const short* Ab = H + (size_t)base * K;

    __shared__ short As[128 * 40];
    __shared__ short Bs[128 * 40];

    int tid = threadIdx.x;
    int wave = tid >> 6, lane = tid & 63;
    int wm = (wave & 1) * 64, wn = (wave >> 1) * 64;
    int fr = lane & 15, fk = (lane >> 4) * 8;

    float4v acc[4][4];
#pragma unroll
    for (int i = 0; i < 4; i++)
#pragma unroll
        for (int j = 0; j < 4; j++) acc[i][j] = (float4v)0.f;

    int r0 = tid >> 2;
    int kq = (tid & 3) * 8;
    const short* arow[2]; const short* brow[2];
#pragma unroll
    for (int ii = 0; ii < 2; ii++) {
        int r = r0 + ii * 64;
        int rr = min(row0 + r, count - 1);
        arow[ii] = Ab + (size_t)rr * K;
        brow[ii] = B + (size_t)(col0 + r) * K;
    }

    for (int k0 = 0; k0 < K; k0 += 32) {
#pragma unroll
        for (int ii = 0; ii < 2; ii++) {
            int r = r0 + ii * 64;
            *(int4*)&As[r * 40 + kq] = *(const int4*)(arow[ii] + k0 + kq);
            *(int4*)&Bs[r * 40 + kq] = *(const int4*)(brow[ii] + k0 + kq);
        }
        __syncthreads();
        short8 a[4], b[4];
#pragma unroll
        for (int i = 0; i < 4; i++) a[i] = *(const short8*)&As[(wm + i * 16 + fr) * 40 + fk];
#pragma unroll
        for (int j = 0; j < 4; j++) b[j] = *(const short8*)&Bs[(wn + j * 16 + fr) * 40 + fk];
#pragma unroll
        for (int i = 0; i < 4; i++)
#pragma unroll
            for (int j = 0; j < 4; j++)
                acc[i][j] = __builtin_amdgcn_mfma_f32_16x16x32_bf16(a[i], b[j], acc[i][j], 0, 0, 0);
        __syncthreads();
    }

    int erow = (lane >> 4) * 4;
    int ecol = lane & 15;
#pragma unroll
    for (int i = 0; i < 4; i++)
#pragma unroll
        for (int j = 0; j < 4; j++)
#pragma unroll
            for (int r = 0; r < 4; r++) {
                int row = wm + i * 16 + erow + r;
                if (row0 + row < count) {
                    float v = acc[i][j][r];
                    int col = col0 + wn + j * 16 + ecol;
                    if (counts) {
                        int t = tok_list[base + row0 + row];
                        atomicAdd(&out[(size_t)t * D_MODEL + col], tok_w[base + row0 + row] * v);
                    } else {
                        out[(size_t)(row0 + row) * D_MODEL + col] = gate[row0 + row] * v;
                    }
                }
            }
}

// ---------------------------------------------------------------- host
extern "C" void kernel_launch(void* const* d_in, const int* in_sizes, int n_in,
                              void* d_out, int out_size, void* d_ws, size_t ws_size,
                              hipStream_t stream) {
    const float* x     = (const float*)d_in[0];
    const float* gw    = (const float*)d_in[1];
    const float* egu   = (const float*)d_in[2];
    const float* edown = (const float*)d_in[3];
    const float* sgu   = (const float*)d_in[4];
    const float* sdown = (const float*)d_in[5];
    const float* sgate = (const float*)d_in[6];
    float* out = (float*)d_out;
    char* ws = (char*)d_ws;

    // workspace layout (bytes)
    const size_t XB_OFF     = 0;                               // 4096*1024*2
    const size_t WGU_OFF    = XB_OFF     + (size_t)4096*1024*2;       // 16*2048*1024*2
    const size_t WDOWN_OFF  = WGU_OFF    + (size_t)16*2048*1024*2;    // 16*1024*1024*2
    const size_t WSGU_OFF   = WDOWN_OFF  + (size_t)16*1024*1024*2;    // 4096*1024*2
    const size_t WSDOWN_OFF = WSGU_OFF   + (size_t)4096*1024*2;       // 1024*2048*2
    const size_t HEXP_OFF   = WSDOWN_OFF + (size_t)1024*2048*2;       // 8192*1024*2
    const size_t HSH_OFF    = HEXP_OFF   + (size_t)8192*1024*2;       // 4096*2048*2
    const size_t TID_OFF    = HSH_OFF    + (size_t)4096*2048*2;       // 4096*2*4
    const size_t TW_OFF     = TID_OFF    + 4096*2*4;
    const size_t GATE_OFF   = TW_OFF     + 4096*2*4;
    const size_t TOKL_OFF   = GATE_OFF   + 4096*4;
    const size_t TOKW_OFF   = TOKL_OFF   + 8192*4;
    const size_t CNT_OFF    = TOKW_OFF   + 8192*4;
    const size_t OFFS_OFF   = CNT_OFF    + 256;
    const size_t CUR_OFF    = OFFS_OFF   + 256;

    short* xb      = (short*)(ws + XB_OFF);
    short* wgu_b   = (short*)(ws + WGU_OFF);
    short* wdown_b = (short*)(ws + WDOWN_OFF);
    short* wsgu_b  = (short*)(ws + WSGU_OFF);
    short* wsdn_b  = (short*)(ws + WSDOWN_OFF);
    short* h_exp   = (short*)(ws + HEXP_OFF);
    short* h_sh    = (short*)(ws + HSH_OFF);
    int*   topk_id = (int*)(ws + TID_OFF);
    float* topk_w  = (float*)(ws + TW_OFF);
    float* gate    = (float*)(ws + GATE_OFF);
    int*   tok_l   = (int*)(ws + TOKL_OFF);
    float* tok_w   = (float*)(ws + TOKW_OFF);
    int*   counts  = (int*)(ws + CNT_OFF);
    int*   offsets = (int*)(ws + OFFS_OFF);
    int*   cursor  = (int*)(ws + CUR_OFF);

    hipMemsetAsync(counts, 0, 64, stream);

    // weight fp32 -> bf16 (every call; ws is re-poisoned)
    {
        int n1 = 16 * 2 * D_FF * D_MODEL;
        convert_kernel<<<n1 / 2048, 256, 0, stream>>>(egu, wgu_b, n1);
        int n2 = 16 * D_MODEL * D_FF;
        convert_kernel<<<n2 / 2048, 256, 0, stream>>>(edown, wdown_b, n2);
        int n3 = 2 * D_FF_SH * D_MODEL;
        convert_kernel<<<n3 / 2048, 256, 0, stream>>>(sgu, wsgu_b, n3);
        int n4 = D_MODEL * D_FF_SH;
        convert_kernel<<<n4 / 2048, 256, 0, stream>>>(sdown, wsdn_b, n4);
    }

    router_kernel<<<T_TOKENS / 4, 256, 0, stream>>>(x, gw, sgate, xb, topk_id, topk_w, gate, counts);
    offsets_kernel<<<1, 64, 0, stream>>>(counts, offsets, cursor);
    scatter_kernel<<<T_TOKENS / 256, 256, 0, stream>>>(topk_id, topk_w, cursor, tok_l, tok_w);

    // expert gemm1: h = silu(g)*u   (grid: worst-case row tiles, early exit)
    gemm1_kernel<<<dim3(32, D_FF / 128, 16), 256, 0, stream>>>(
        xb, wgu_b, h_exp, tok_l, offsets, counts, D_FF);
    // shared gemm1
    gemm1_kernel<<<dim3(T_TOKENS / 128, D_FF_SH / 128, 1), 256, 0, stream>>>(
        xb, wsgu_b, h_sh, nullptr, nullptr, nullptr, D_FF_SH);

    // shared gemm2 first: plain store initializes every out element
    gemm2_kernel<<<dim3(T_TOKENS / 128, D_MODEL / 128, 1), 256, 0, stream>>>(
        h_sh, D_FF_SH, wsdn_b, out, nullptr, nullptr, nullptr, nullptr, gate);
    // expert gemm2: atomic weighted scatter-add on top
    gemm2_kernel<<<dim3(32, D_MODEL / 128, 16), 256, 0, stream>>>(
        h_exp, D_FF, wdown_b, out, tok_l, tok_w, offsets, counts, nullptr);
}

// Round 3
// 1068.682 us; speedup vs baseline: 1.1470x; 1.1470x over previous
//
#include <hip/hip_runtime.h>
#include <hip/hip_bf16.h>

#define T_TOKENS 4096
#define D_MODEL  1024
#define N_EXP    16
#define D_FF     1024
#define D_FF_SH  2048
#define MAX_TILES 80   // sum ceil(count_e/128) <= 8192/128 + 15 = 79

typedef __attribute__((ext_vector_type(8))) short short8;
typedef __attribute__((ext_vector_type(4))) float float4v;

__device__ __forceinline__ short f2bf(float f) {
    union { float f; unsigned u; } c; c.f = f;
    unsigned u = c.u + 0x7fffu + ((c.u >> 16) & 1u);
    return (short)(u >> 16);
}

// async global->LDS, 16B per lane. LDS dest is wave-uniform base + lane*16;
// we pass per-lane base+tid*16 which matches that mapping (rows of 64B, unpadded).
__device__ __forceinline__ void gload16(const void* g, void* l) {
    __builtin_amdgcn_global_load_lds(
        (const __attribute__((address_space(1))) void*)g,
        (__attribute__((address_space(3))) void*)l, 16, 0, 0);
}

// ---------------------------------------------------------------- convert (all 4 weights, one dispatch)
__global__ __launch_bounds__(256) void convert_all_kernel(
    const float* __restrict__ s0, short* __restrict__ d0,   // egu   33554432
    const float* __restrict__ s1, short* __restrict__ d1,   // edown 16777216
    const float* __restrict__ s2, short* __restrict__ d2,   // sgu    4194304
    const float* __restrict__ s3, short* __restrict__ d3) { // sdown  2097152
    int c = blockIdx.x * 256 + threadIdx.x;   // chunk of 8 elements
    const float* s; short* d; int off;
    if      (c < 4194304) { s = s0; d = d0; off = c; }
    else if (c < 6291456) { s = s1; d = d1; off = c - 4194304; }
    else if (c < 6815744) { s = s2; d = d2; off = c - 6291456; }
    else                  { s = s3; d = d3; off = c - 6815744; }
    size_t i = (size_t)off * 8;
    float4 a = *(const float4*)(s + i);
    float4 b = *(const float4*)(s + i + 4);
    union { short sh[8]; int4 v; } p;
    p.sh[0] = f2bf(a.x); p.sh[1] = f2bf(a.y); p.sh[2] = f2bf(a.z); p.sh[3] = f2bf(a.w);
    p.sh[4] = f2bf(b.x); p.sh[5] = f2bf(b.y); p.sh[6] = f2bf(b.z); p.sh[7] = f2bf(b.w);
    *(int4*)(d + i) = p.v;
}

// ---------------------------------------------------------------- router (fp32 exact)
__global__ __launch_bounds__(256) void router_kernel(
    const float* __restrict__ x, const float* __restrict__ gw, const float* __restrict__ sgw,
    short* __restrict__ xb, int* __restrict__ topk_id, float* __restrict__ topk_w,
    float* __restrict__ gate, int* __restrict__ counts) {
    int wave = threadIdx.x >> 6, lane = threadIdx.x & 63;
    int t = blockIdx.x * 4 + wave;
    const float* xt = x + (size_t)t * D_MODEL;
    float acc[17];
#pragma unroll
    for (int e = 0; e < 17; e++) acc[e] = 0.f;
#pragma unroll
    for (int i = 0; i < 16; i++) {
        int d = lane + i * 64;
        float xv = xt[d];
        xb[(size_t)t * D_MODEL + d] = f2bf(xv);
#pragma unroll
        for (int e = 0; e < 16; e++) acc[e] += xv * gw[e * D_MODEL + d];
        acc[16] += xv * sgw[d];
    }
#pragma unroll
    for (int e = 0; e < 17; e++)
        for (int off = 32; off; off >>= 1) acc[e] += __shfl_xor(acc[e], off);
    if (lane == 0) {
        float v1 = -1e30f, v2 = -1e30f; int i1 = 0, i2 = 0;
#pragma unroll
        for (int e = 0; e < 16; e++) {
            float v = acc[e];
            if (v > v1) { v2 = v1; i2 = i1; v1 = v; i1 = e; }
            else if (v > v2) { v2 = v; i2 = e; }
        }
        float e2 = expf(v2 - v1);
        float s = 1.f + e2;
        topk_id[t * 2] = i1; topk_id[t * 2 + 1] = i2;
        topk_w[t * 2] = 1.f / s; topk_w[t * 2 + 1] = e2 / s;
        gate[t] = 1.f / (1.f + expf(-acc[16]));
        atomicAdd(&counts[i1], 1); atomicAdd(&counts[i2], 1);
    }
}

// ---------------------------------------------------------------- offsets + live-tile map
__global__ void offsets_kernel(const int* __restrict__ counts, int* __restrict__ offsets,
                               int* __restrict__ cursor, int* __restrict__ tile_map,
                               int* __restrict__ n_tiles) {
    if (threadIdx.x == 0) {
        int off = 0, nt = 0;
        for (int e = 0; e < N_EXP; e++) {
            offsets[e] = off; cursor[e] = off;
            int c = counts[e];
            for (int r = 0; r < c; r += 128) tile_map[nt++] = (e << 16) | (r >> 7);
            off += c;
        }
        n_tiles[0] = nt;
    }
}

__global__ __launch_bounds__(256) void scatter_kernel(
    const int* __restrict__ topk_id, const float* __restrict__ topk_w,
    int* __restrict__ cursor, int* __restrict__ tok_list, float* __restrict__ tok_w,
    int* __restrict__ slot_of) {
    int t = blockIdx.x * 256 + threadIdx.x;
#pragma unroll
    for (int k = 0; k < 2; k++) {
        int e = topk_id[t * 2 + k];
        int pos = atomicAdd(&cursor[e], 1);
        tok_list[pos] = t;
        tok_w[pos] = topk_w[t * 2 + k];
        slot_of[t * 2 + k] = pos;
    }
}

// ---------------------------------------------------------------- GEMM1 (expert + shared, one dispatch)
// grid (112, 16): bx<80 -> expert tile (by<8), bx>=80 -> shared tile row (bx-80)*128, by<16.
__global__ __launch_bounds__(256, 3) void gemm1_kernel(
    const short* __restrict__ xb,
    const short* __restrict__ Wexp,   // [16][2048][1024]
    const short* __restrict__ Wsh,    // [4096][1024]
    short* __restrict__ Hexp,         // [8192][1024]
    short* __restrict__ Hsh,          // [4096][2048]
    const int* __restrict__ tok_list,
    const int* __restrict__ offsets, const int* __restrict__ counts,
    const int* __restrict__ tile_map, const int* __restrict__ n_tiles) {
    int bx = blockIdx.x, by = blockIdx.y;
    int count, row0, dff;
    const int* idx = nullptr;
    const short* Wg; short* Hout;
    if (bx < MAX_TILES) {
        if (by >= 8 || bx >= n_tiles[0]) return;
        int tm = tile_map[bx];
        int e = tm >> 16; row0 = (tm & 0xffff) << 7;
        count = counts[e];
        int base = offsets[e];
        idx = tok_list + base;
        Wg = Wexp + (size_t)e * 2 * D_FF * D_MODEL;
        Hout = Hexp + (size_t)base * D_FF;
        dff = D_FF;
    } else {
        row0 = (bx - MAX_TILES) * 128; count = T_TOKENS;
        Wg = Wsh; Hout = Hsh; dff = D_FF_SH;
    }
    int col0 = by * 128;
    const short* Wu = Wg + (size_t)dff * D_MODEL;

    __shared__ short As[128 * 32];
    __shared__ short Bg[128 * 32];
    __shared__ short Bu[128 * 32];

    int tid = threadIdx.x;
    int wave = tid >> 6, lane = tid & 63;
    int wm = (wave & 1) * 64, wn = (wave >> 1) * 64;
    int fr = lane & 15, fk = (lane >> 4) * 8;

    float4v accg[4][4], accu[4][4];
#pragma unroll
    for (int i = 0; i < 4; i++)
#pragma unroll
        for (int j = 0; j < 4; j++) { accg[i][j] = (float4v)0.f; accu[i][j] = (float4v)0.f; }

    int r0 = tid >> 2;            // staging row 0..63 (+64 for second instr)
    int kq = (tid & 3) * 8;       // 16B chunk within the 64B row
    const short* ar[2]; const short* bg[2]; const short* bu[2];
#pragma unroll
    for (int ii = 0; ii < 2; ii++) {
        int r = r0 + ii * 64;
        int rr = min(row0 + r, count - 1);
        int g = idx ? idx[rr] : rr;
        ar[ii] = xb + (size_t)g * D_MODEL + kq;
        bg[ii] = Wg + (size_t)(col0 + r) * D_MODEL + kq;
        bu[ii] = Wu + (size_t)(col0 + r) * D_MODEL + kq;
    }
    char* AsB = (char*)As; char* BgB = (char*)Bg; char* BuB = (char*)Bu;
    int loff = tid * 16;

    for (int k0 = 0; k0 < D_MODEL; k0 += 32) {
        gload16(ar[0] + k0, AsB + loff);
        gload16(ar[1] + k0, AsB + 4096 + loff);
        gload16(bg[0] + k0, BgB + loff);
        gload16(bg[1] + k0, BgB + 4096 + loff);
        gload16(bu[0] + k0, BuB + loff);
        gload16(bu[1] + k0, BuB + 4096 + loff);
        __syncthreads();   // compiler drains vmcnt before barrier
        short8 af[4], bgf[4], buf[4];
#pragma unroll
        for (int i = 0; i < 4; i++) af[i] = *(const short8*)&As[(wm + i * 16 + fr) * 32 + fk];
#pragma unroll
        for (int j = 0; j < 4; j++) {
            bgf[j] = *(const short8*)&Bg[(wn + j * 16 + fr) * 32 + fk];
            buf[j] = *(const short8*)&Bu[(wn + j * 16 + fr) * 32 + fk];
        }
#pragma unroll
        for (int i = 0; i < 4; i++)
#pragma unroll
            for (int j = 0; j < 4; j++) {
                accg[i][j] = __builtin_amdgcn_mfma_f32_16x16x32_bf16(af[i], bgf[j], accg[i][j], 0, 0, 0);
                accu[i][j] = __builtin_amdgcn_mfma_f32_16x16x32_bf16(af[i], buf[j], accu[i][j], 0, 0, 0);
            }
        __syncthreads();
    }

    int erow = (lane >> 4) * 4;
    int ecol = lane & 15;
#pragma unroll
    for (int i = 0; i < 4; i++)
#pragma unroll
        for (int j = 0; j < 4; j++)
#pragma unroll
            for (int r = 0; r < 4; r++) {
                int row = wm + i * 16 + erow + r;
                if (row0 + row < count) {
                    float g = accg[i][j][r], u = accu[i][j][r];
                    float h = g / (1.f + expf(-g)) * u;
                    Hout[(size_t)(row0 + row) * dff + col0 + wn + j * 16 + ecol] = f2bf(h);
                }
            }
}

// ---------------------------------------------------------------- GEMM2 (expert + shared, one dispatch)
// grid (112, 8). Expert part: pre-weighted plain stores to oslots. Shared: gated stores to out.
__global__ __launch_bounds__(256, 4) void gemm2_kernel(
    const short* __restrict__ Hexp, const short* __restrict__ Hsh,
    const short* __restrict__ Wdexp,  // [16][1024][1024]
    const short* __restrict__ Wdsh,   // [1024][2048]
    float* __restrict__ oslots,       // [8192][1024]
    float* __restrict__ out,          // [4096][1024]
    const float* __restrict__ tok_w, const float* __restrict__ gate,
    const int* __restrict__ offsets, const int* __restrict__ counts,
    const int* __restrict__ tile_map, const int* __restrict__ n_tiles) {
    int bx = blockIdx.x, by = blockIdx.y;
    int count, row0, K, base;
    const short* Ab; const short* B;
    bool shared_part;
    if (bx < MAX_TILES) {
        if (bx >= n_tiles[0]) return;
        int tm = tile_map[bx];
        int e = tm >> 16; row0 = (tm & 0xffff) << 7;
        count = counts[e]; base = offsets[e];
        Ab = Hexp + (size_t)base * D_FF; K = D_FF;
        B = Wdexp + (size_t)e * D_MODEL * D_FF;
        shared_part = false;
    } else {
        row0 = (bx - MAX_TILES) * 128; count = T_TOKENS; base = 0;
        Ab = Hsh; K = D_FF_SH; B = Wdsh; shared_part = true;
    }
    int col0 = by * 128;

    __shared__ short As[128 * 32];
    __shared__ short Bs[128 * 32];

    int tid = threadIdx.x;
    int wave = tid >> 6, lane = tid & 63;
    int wm = (wave & 1) * 64, wn = (wave >> 1) * 64;
    int fr = lane & 15, fk = (lane >> 4) * 8;

    float4v acc[4][4];
#pragma unroll
    for (int i = 0; i < 4; i++)
#pragma unroll
        for (int j = 0; j < 4; j++) acc[i][j] = (float4v)0.f;

    int r0 = tid >> 2;
    int kq = (tid & 3) * 8;
    const short* ar[2]; const short* br[2];
#pragma unroll
    for (int ii = 0; ii < 2; ii++) {
        int r = r0 + ii * 64;
        int rr = min(row0 + r, count - 1);
        ar[ii] = Ab + (size_t)rr * K + kq;
        br[ii] = B + (size_t)(col0 + r) * K + kq;
    }
    char* AsB = (char*)As; char* BsB = (char*)Bs;
    int loff = tid * 16;

    for (int k0 = 0; k0 < K; k0 += 32) {
        gload16(ar[0] + k0, AsB + loff);
        gload16(ar[1] + k0, AsB + 4096 + loff);
        gload16(br[0] + k0, BsB + loff);
        gload16(br[1] + k0, BsB + 4096 + loff);
        __syncthreads();
        short8 af[4], bf[4];
#pragma unroll
        for (int i = 0; i < 4; i++) af[i] = *(const short8*)&As[(wm + i * 16 + fr) * 32 + fk];
#pragma unroll
        for (int j = 0; j < 4; j++) bf[j] = *(const short8*)&Bs[(wn + j * 16 + fr) * 32 + fk];
#pragma unroll
        for (int i = 0; i < 4; i++)
#pragma unroll
            for (int j = 0; j < 4; j++)
                acc[i][j] = __builtin_amdgcn_mfma_f32_16x16x32_bf16(af[i], bf[j], acc[i][j], 0, 0, 0);
        __syncthreads();
    }

    int erow = (lane >> 4) * 4;
    int ecol = lane & 15;
#pragma unroll
    for (int i = 0; i < 4; i++)
#pragma unroll
        for (int j = 0; j < 4; j++)
#pragma unroll
            for (int r = 0; r < 4; r++) {
                int row = wm + i * 16 + erow + r;
                if (row0 + row < count) {
                    float v = acc[i][j][r];
                    int col = col0 + wn + j * 16 + ecol;
                    if (!shared_part) {
                        int slot = base + row0 + row;
                        oslots[(size_t)slot * D_MODEL + col] = tok_w[slot] * v;
                    } else {
                        out[(size_t)(row0 + row) * D_MODEL + col] = gate[row0 + row] * v;
                    }
                }
            }
}

// ---------------------------------------------------------------- combine: out[t] += oslots[sA] + oslots[sB]
__global__ __launch_bounds__(256) void combine_kernel(
    float* __restrict__ out, const float* __restrict__ oslots,
    const int* __restrict__ slot_of) {
    int t = blockIdx.x;
    int sA = slot_of[t * 2], sB = slot_of[t * 2 + 1];
    int d = threadIdx.x * 4;
    float4 o = *(float4*)&out[(size_t)t * D_MODEL + d];
    float4 a = *(const float4*)&oslots[(size_t)sA * D_MODEL + d];
    float4 b = *(const float4*)&oslots[(size_t)sB * D_MODEL + d];
    o.x += a.x + b.x; o.y += a.y + b.y; o.z += a.z + b.z; o.w += a.w + b.w;
    *(float4*)&out[(size_t)t * D_MODEL + d] = o;
}

// ---------------------------------------------------------------- host
extern "C" void kernel_launch(void* const* d_in, const int* in_sizes, int n_in,
                              void* d_out, int out_size, void* d_ws, size_t ws_size,
                              hipStream_t stream) {
    const float* x     = (const float*)d_in[0];
    const float* gw    = (const float*)d_in[1];
    const float* egu   = (const float*)d_in[2];
    const float* edown = (const float*)d_in[3];
    const float* sgu   = (const float*)d_in[4];
    const float* sdown = (const float*)d_in[5];
    const float* sgate = (const float*)d_in[6];
    float* out = (float*)d_out;
    char* ws = (char*)d_ws;

    // workspace layout (bytes), ~189 MB total
    const size_t XB_OFF     = 0;                                      // 8 MB
    const size_t WGU_OFF    = XB_OFF     + (size_t)4096*1024*2;       // 64 MB
    const size_t WDOWN_OFF  = WGU_OFF    + (size_t)16*2048*1024*2;    // 32 MB
    const size_t WSGU_OFF   = WDOWN_OFF  + (size_t)16*1024*1024*2;    // 8 MB
    const size_t WSDOWN_OFF = WSGU_OFF   + (size_t)4096*1024*2;       // 4 MB
    const size_t HEXP_OFF   = WSDOWN_OFF + (size_t)1024*2048*2;       // 16 MB
    const size_t HSH_OFF    = HEXP_OFF   + (size_t)8192*1024*2;       // 16 MB
    const size_t OSLOT_OFF  = HSH_OFF    + (size_t)4096*2048*2;       // 32 MB
    const size_t TID_OFF    = OSLOT_OFF  + (size_t)8192*1024*4;
    const size_t TW_OFF     = TID_OFF    + 4096*2*4;
    const size_t GATE_OFF   = TW_OFF     + 4096*2*4;
    const size_t TOKL_OFF   = GATE_OFF   + 4096*4;
    const size_t TOKW_OFF   = TOKL_OFF   + 8192*4;
    const size_t SLOT_OFF   = TOKW_OFF   + 8192*4;
    const size_t CNT_OFF    = SLOT_OFF   + 8192*4;
    const size_t OFFS_OFF   = CNT_OFF    + 256;
    const size_t CUR_OFF    = OFFS_OFF   + 256;
    const size_t TMAP_OFF   = CUR_OFF    + 256;
    const size_t NT_OFF     = TMAP_OFF   + 512;

    short* xb      = (short*)(ws + XB_OFF);
    short* wgu_b   = (short*)(ws + WGU_OFF);
    short* wdown_b = (short*)(ws + WDOWN_OFF);
    short* wsgu_b  = (short*)(ws + WSGU_OFF);
    short* wsdn_b  = (short*)(ws + WSDOWN_OFF);
    short* h_exp   = (short*)(ws + HEXP_OFF);
    short* h_sh    = (short*)(ws + HSH_OFF);
    float* oslots  = (float*)(ws + OSLOT_OFF);
    int*   topk_id = (int*)(ws + TID_OFF);
    float* topk_w  = (float*)(ws + TW_OFF);
    float* gate    = (float*)(ws + GATE_OFF);
    int*   tok_l   = (int*)(ws + TOKL_OFF);
    float* tok_w   = (float*)(ws + TOKW_OFF);
    int*   slot_of = (int*)(ws + SLOT_OFF);
    int*   counts  = (int*)(ws + CNT_OFF);
    int*   offsets = (int*)(ws + OFFS_OFF);
    int*   cursor  = (int*)(ws + CUR_OFF);
    int*   tmap    = (int*)(ws + TMAP_OFF);
    int*   ntiles  = (int*)(ws + NT_OFF);

    hipMemsetAsync(counts, 0, 64, stream);

    convert_all_kernel<<<27648, 256, 0, stream>>>(egu, wgu_b, edown, wdown_b,
                                                  sgu, wsgu_b, sdown, wsdn_b);
    router_kernel<<<T_TOKENS / 4, 256, 0, stream>>>(x, gw, sgate, xb, topk_id, topk_w, gate, counts);
    offsets_kernel<<<1, 64, 0, stream>>>(counts, offsets, cursor, tmap, ntiles);
    scatter_kernel<<<T_TOKENS / 256, 256, 0, stream>>>(topk_id, topk_w, cursor, tok_l, tok_w, slot_of);

    gemm1_kernel<<<dim3(MAX_TILES + 32, 16), 256, 0, stream>>>(
        xb, wgu_b, wsgu_b, h_exp, h_sh, tok_l, offsets, counts, tmap, ntiles);

    gemm2_kernel<<<dim3(MAX_TILES + 32, 8), 256, 0, stream>>>(
        h_exp, h_sh, wdown_b, wsdn_b, oslots, out, tok_w, gate, offsets, counts, tmap, ntiles);

    combine_kernel<<<T_TOKENS, 256, 0, stream>>>(out, oslots, slot_of);
}

// Round 4
// 693.165 us; speedup vs baseline: 1.7684x; 1.5417x over previous
//
#include <hip/hip_runtime.h>
#include <hip/hip_bf16.h>

#define T_TOKENS 4096
#define D_MODEL  1024
#define N_EXP    16
#define D_FF     1024
#define D_FF_SH  2048
#define MAX_T256 48   // sum ceil(count_e/256) <= 8192/256 + 16 = 48

typedef __attribute__((ext_vector_type(8))) short short8;
typedef __attribute__((ext_vector_type(4))) float float4v;

__device__ __forceinline__ short f2bf(float f) {
    union { float f; unsigned u; } c; c.f = f;
    unsigned u = c.u + 0x7fffu + ((c.u >> 16) & 1u);
    return (short)(u >> 16);
}

// async global->LDS, 16B per lane; LDS dest = wave-uniform base + lane*16.
__device__ __forceinline__ void gload16(const void* g, void* l) {
    __builtin_amdgcn_global_load_lds(
        (const __attribute__((address_space(1))) void*)g,
        (__attribute__((address_space(3))) void*)l, 16, 0, 0);
}

// ---------------------------------------------------------------- convert (all 4 weights, one dispatch)
__global__ __launch_bounds__(256) void convert_all_kernel(
    const float* __restrict__ s0, short* __restrict__ d0,   // egu   33554432
    const float* __restrict__ s1, short* __restrict__ d1,   // edown 16777216
    const float* __restrict__ s2, short* __restrict__ d2,   // sgu    4194304
    const float* __restrict__ s3, short* __restrict__ d3) { // sdown  2097152
    int c = blockIdx.x * 256 + threadIdx.x;   // chunk of 8 elements
    const float* s; short* d; int off;
    if      (c < 4194304) { s = s0; d = d0; off = c; }
    else if (c < 6291456) { s = s1; d = d1; off = c - 4194304; }
    else if (c < 6815744) { s = s2; d = d2; off = c - 6291456; }
    else                  { s = s3; d = d3; off = c - 6815744; }
    size_t i = (size_t)off * 8;
    float4 a = *(const float4*)(s + i);
    float4 b = *(const float4*)(s + i + 4);
    union { short sh[8]; int4 v; } p;
    p.sh[0] = f2bf(a.x); p.sh[1] = f2bf(a.y); p.sh[2] = f2bf(a.z); p.sh[3] = f2bf(a.w);
    p.sh[4] = f2bf(b.x); p.sh[5] = f2bf(b.y); p.sh[6] = f2bf(b.z); p.sh[7] = f2bf(b.w);
    *(int4*)(d + i) = p.v;
}

// ---------------------------------------------------------------- router (fp32 exact)
__global__ __launch_bounds__(256) void router_kernel(
    const float* __restrict__ x, const float* __restrict__ gw, const float* __restrict__ sgw,
    short* __restrict__ xb, int* __restrict__ topk_id, float* __restrict__ topk_w,
    float* __restrict__ gate, int* __restrict__ counts) {
    int wave = threadIdx.x >> 6, lane = threadIdx.x & 63;
    int t = blockIdx.x * 4 + wave;
    const float* xt = x + (size_t)t * D_MODEL;
    float acc[17];
#pragma unroll
    for (int e = 0; e < 17; e++) acc[e] = 0.f;
#pragma unroll
    for (int i = 0; i < 16; i++) {
        int d = lane + i * 64;
        float xv = xt[d];
        xb[(size_t)t * D_MODEL + d] = f2bf(xv);
#pragma unroll
        for (int e = 0; e < 16; e++) acc[e] += xv * gw[e * D_MODEL + d];
        acc[16] += xv * sgw[d];
    }
#pragma unroll
    for (int e = 0; e < 17; e++)
        for (int off = 32; off; off >>= 1) acc[e] += __shfl_xor(acc[e], off);
    if (lane == 0) {
        float v1 = -1e30f, v2 = -1e30f; int i1 = 0, i2 = 0;
#pragma unroll
        for (int e = 0; e < 16; e++) {
            float v = acc[e];
            if (v > v1) { v2 = v1; i2 = i1; v1 = v; i1 = e; }
            else if (v > v2) { v2 = v; i2 = e; }
        }
        float e2 = expf(v2 - v1);
        float s = 1.f + e2;
        topk_id[t * 2] = i1; topk_id[t * 2 + 1] = i2;
        topk_w[t * 2] = 1.f / s; topk_w[t * 2 + 1] = e2 / s;
        gate[t] = 1.f / (1.f + expf(-acc[16]));
        atomicAdd(&counts[i1], 1); atomicAdd(&counts[i2], 1);
    }
}

// ---------------------------------------------------------------- offsets + live 256-row-tile map
__global__ void offsets_kernel(const int* __restrict__ counts, int* __restrict__ offsets,
                               int* __restrict__ cursor, int* __restrict__ tile_map,
                               int* __restrict__ n_tiles) {
    if (threadIdx.x == 0) {
        int off = 0, nt = 0;
        for (int e = 0; e < N_EXP; e++) {
            offsets[e] = off; cursor[e] = off;
            int c = counts[e];
            for (int r = 0; r < c; r += 256) tile_map[nt++] = (e << 16) | (r >> 8);
            off += c;
        }
        n_tiles[0] = nt;
    }
}

__global__ __launch_bounds__(256) void scatter_kernel(
    const int* __restrict__ topk_id, const float* __restrict__ topk_w,
    int* __restrict__ cursor, int* __restrict__ tok_list, float* __restrict__ tok_w,
    int* __restrict__ slot_of) {
    int t = blockIdx.x * 256 + threadIdx.x;
#pragma unroll
    for (int k = 0; k < 2; k++) {
        int e = topk_id[t * 2 + k];
        int pos = atomicAdd(&cursor[e], 1);
        tok_list[pos] = t;
        tok_w[pos] = topk_w[t * 2 + k];
        slot_of[t * 2 + k] = pos;
    }
}

// ---------------------------------------------------------------- GEMM1: 256x128 tile, fused gate+up
// grid (64,16): bx<48 expert tiles (by<8); bx in 48..63 -> shared row-tile, by<16.
// 512 threads = 8 waves, wave-tile 64x64 (dual acc). LDS: 2 x 32KB slices (A16K|Bg8K|Bu8K).
__global__ __launch_bounds__(512, 2) void gemm1_kernel(
    const short* __restrict__ xb,
    const short* __restrict__ Wexp,   // [16][2048][1024]
    const short* __restrict__ Wsh,    // [4096][1024]
    short* __restrict__ Hexp,         // [8192][1024]
    short* __restrict__ Hsh,          // [4096][2048]
    const int* __restrict__ tok_list,
    const int* __restrict__ offsets, const int* __restrict__ counts,
    const int* __restrict__ tile_map, const int* __restrict__ n_tiles) {
    int bx = blockIdx.x, by = blockIdx.y;
    int count, row0, dff;
    const int* idx = nullptr;
    const short* Wg; short* Hout;
    if (bx < MAX_T256) {
        if (by >= 8 || bx >= n_tiles[0]) return;
        int tm = tile_map[bx];
        int e = tm >> 16; row0 = (tm & 0xffff) << 8;
        count = counts[e];
        int base = offsets[e];
        idx = tok_list + base;
        Wg = Wexp + (size_t)e * 2 * D_FF * D_MODEL;
        Hout = Hexp + (size_t)base * D_FF;
        dff = D_FF;
    } else {
        row0 = (bx - MAX_T256) * 256; count = T_TOKENS;
        Wg = Wsh; Hout = Hsh; dff = D_FF_SH;
    }
    int col0 = by * 128;
    const short* Wu = Wg + (size_t)dff * D_MODEL;

    __shared__ char lds[65536];

    int t = threadIdx.x;
    int wave = t >> 6, lane = t & 63;
    int wm = (wave & 3) * 64, wn = (wave >> 2) * 64;
    int fr = lane & 15, fk2 = (lane >> 4) * 16;   // byte offset of 8-short chunk

    float4v accg[4][4], accu[4][4];
#pragma unroll
    for (int i = 0; i < 4; i++)
#pragma unroll
        for (int j = 0; j < 4; j++) { accg[i][j] = (float4v)0.f; accu[i][j] = (float4v)0.f; }

    // staging: thread t handles row (t>>2) for each region, 16B chunk (t&3)
    int rA = t >> 2;              // 0..127
    int cq = (t & 3) * 8;         // shorts
    int r0c = min(row0 + rA, count - 1);
    int r1c = min(row0 + rA + 128, count - 1);
    int g0 = idx ? idx[r0c] : r0c;
    int g1 = idx ? idx[r1c] : r1c;
    const short* aP0 = xb + (size_t)g0 * D_MODEL + cq;
    const short* aP1 = xb + (size_t)g1 * D_MODEL + cq;
    const short* bgP = Wg + (size_t)(col0 + rA) * D_MODEL + cq;
    const short* buP = Wu + (size_t)(col0 + rA) * D_MODEL + cq;
    int lo = t * 16;              // 0..8191

    // prologue: issue slice 0 into buf 0
    gload16(aP0, lds + lo);
    gload16(aP1, lds + 8192 + lo);
    gload16(bgP, lds + 16384 + lo);
    gload16(buP, lds + 24576 + lo);

    const int NK = D_MODEL / 32;  // 32 slices
    for (int k = 0; k < NK; k++) {
        __syncthreads();          // drains slice-k DMAs (overlapped by compute(k-1))
        if (k + 1 < NK) {
            int s = ((k + 1) & 1) * 32768;
            int off = (k + 1) * 32;   // shorts
            gload16(aP0 + off, lds + s + lo);
            gload16(aP1 + off, lds + s + 8192 + lo);
            gload16(bgP + off, lds + s + 16384 + lo);
            gload16(buP + off, lds + s + 24576 + lo);
        }
        int sb = (k & 1) * 32768;
        short8 af[4], bgf[4], buf[4];
#pragma unroll
        for (int i = 0; i < 4; i++)
            af[i] = *(const short8*)(lds + sb + (wm + i * 16 + fr) * 64 + fk2);
#pragma unroll
        for (int j = 0; j < 4; j++) {
            bgf[j] = *(const short8*)(lds + sb + 16384 + (wn + j * 16 + fr) * 64 + fk2);
            buf[j] = *(const short8*)(lds + sb + 24576 + (wn + j * 16 + fr) * 64 + fk2);
        }
#pragma unroll
        for (int i = 0; i < 4; i++)
#pragma unroll
            for (int j = 0; j < 4; j++) {
                accg[i][j] = __builtin_amdgcn_mfma_f32_16x16x32_bf16(af[i], bgf[j], accg[i][j], 0, 0, 0);
                accu[i][j] = __builtin_amdgcn_mfma_f32_16x16x32_bf16(af[i], buf[j], accu[i][j], 0, 0, 0);
            }
    }

    int erow = (lane >> 4) * 4;
    int ecol = lane & 15;
#pragma unroll
    for (int i = 0; i < 4; i++)
#pragma unroll
        for (int j = 0; j < 4; j++)
#pragma unroll
            for (int r = 0; r < 4; r++) {
                int row = wm + i * 16 + erow + r;
                if (row0 + row < count) {
                    float g = accg[i][j][r], u = accu[i][j][r];
                    float h = g / (1.f + expf(-g)) * u;
                    Hout[(size_t)(row0 + row) * dff + col0 + wn + j * 16 + ecol] = f2bf(h);
                }
            }
}

// ---------------------------------------------------------------- GEMM2: 256x128 tile
// grid (64,8). Expert: pre-weighted plain stores to oslots. Shared (K=2048): gated stores to out.
__global__ __launch_bounds__(512, 2) void gemm2_kernel(
    const short* __restrict__ Hexp, const short* __restrict__ Hsh,
    const short* __restrict__ Wdexp,  // [16][1024][1024]
    const short* __restrict__ Wdsh,   // [1024][2048]
    float* __restrict__ oslots,       // [8192][1024]
    float* __restrict__ out,          // [4096][1024]
    const float* __restrict__ tok_w, const float* __restrict__ gate,
    const int* __restrict__ offsets, const int* __restrict__ counts,
    const int* __restrict__ tile_map, const int* __restrict__ n_tiles) {
    int bx = blockIdx.x, by = blockIdx.y;
    int count, row0, K, base;
    const short* Ab; const short* B;
    bool shared_part;
    if (bx < MAX_T256) {
        if (bx >= n_tiles[0]) return;
        int tm = tile_map[bx];
        int e = tm >> 16; row0 = (tm & 0xffff) << 8;
        count = counts[e]; base = offsets[e];
        Ab = Hexp + (size_t)base * D_FF; K = D_FF;
        B = Wdexp + (size_t)e * D_MODEL * D_FF;
        shared_part = false;
    } else {
        row0 = (bx - MAX_T256) * 256; count = T_TOKENS; base = 0;
        Ab = Hsh; K = D_FF_SH; B = Wdsh; shared_part = true;
    }
    int col0 = by * 128;

    __shared__ char lds[49152];   // 2 x 24KB slices (A16K|B8K)

    int t = threadIdx.x;
    int wave = t >> 6, lane = t & 63;
    int wm = (wave & 3) * 64, wn = (wave >> 2) * 64;
    int fr = lane & 15, fk2 = (lane >> 4) * 16;

    float4v acc[4][4];
#pragma unroll
    for (int i = 0; i < 4; i++)
#pragma unroll
        for (int j = 0; j < 4; j++) acc[i][j] = (float4v)0.f;

    int rA = t >> 2;
    int cq = (t & 3) * 8;
    int r0c = min(row0 + rA, count - 1);
    int r1c = min(row0 + rA + 128, count - 1);
    const short* aP0 = Ab + (size_t)r0c * K + cq;
    const short* aP1 = Ab + (size_t)r1c * K + cq;
    const short* bP  = B + (size_t)(col0 + rA) * K + cq;
    int lo = t * 16;

    gload16(aP0, lds + lo);
    gload16(aP1, lds + 8192 + lo);
    gload16(bP,  lds + 16384 + lo);

    const int NK = K / 32;        // 32 or 64
    for (int k = 0; k < NK; k++) {
        __syncthreads();
        if (k + 1 < NK) {
            int s = ((k + 1) & 1) * 24576;
            int off = (k + 1) * 32;
            gload16(aP0 + off, lds + s + lo);
            gload16(aP1 + off, lds + s + 8192 + lo);
            gload16(bP + off,  lds + s + 16384 + lo);
        }
        int sb = (k & 1) * 24576;
        short8 af[4], bf[4];
#pragma unroll
        for (int i = 0; i < 4; i++)
            af[i] = *(const short8*)(lds + sb + (wm + i * 16 + fr) * 64 + fk2);
#pragma unroll
        for (int j = 0; j < 4; j++)
            bf[j] = *(const short8*)(lds + sb + 16384 + (wn + j * 16 + fr) * 64 + fk2);
#pragma unroll
        for (int i = 0; i < 4; i++)
#pragma unroll
            for (int j = 0; j < 4; j++)
                acc[i][j] = __builtin_amdgcn_mfma_f32_16x16x32_bf16(af[i], bf[j], acc[i][j], 0, 0, 0);
    }

    int erow = (lane >> 4) * 4;
    int ecol = lane & 15;
#pragma unroll
    for (int i = 0; i < 4; i++)
#pragma unroll
        for (int j = 0; j < 4; j++)
#pragma unroll
            for (int r = 0; r < 4; r++) {
                int row = wm + i * 16 + erow + r;
                if (row0 + row < count) {
                    float v = acc[i][j][r];
                    int col = col0 + wn + j * 16 + ecol;
                    if (!shared_part) {
                        int slot = base + row0 + row;
                        oslots[(size_t)slot * D_MODEL + col] = tok_w[slot] * v;
                    } else {
                        out[(size_t)(row0 + row) * D_MODEL + col] = gate[row0 + row] * v;
                    }
                }
            }
}

// ---------------------------------------------------------------- combine: out[t] += oslots[sA] + oslots[sB]
__global__ __launch_bounds__(256) void combine_kernel(
    float* __restrict__ out, const float* __restrict__ oslots,
    const int* __restrict__ slot_of) {
    int t = blockIdx.x;
    int sA = slot_of[t * 2], sB = slot_of[t * 2 + 1];
    int d = threadIdx.x * 4;
    float4 o = *(float4*)&out[(size_t)t * D_MODEL + d];
    float4 a = *(const float4*)&oslots[(size_t)sA * D_MODEL + d];
    float4 b = *(const float4*)&oslots[(size_t)sB * D_MODEL + d];
    o.x += a.x + b.x; o.y += a.y + b.y; o.z += a.z + b.z; o.w += a.w + b.w;
    *(float4*)&out[(size_t)t * D_MODEL + d] = o;
}

// ---------------------------------------------------------------- host
extern "C" void kernel_launch(void* const* d_in, const int* in_sizes, int n_in,
                              void* d_out, int out_size, void* d_ws, size_t ws_size,
                              hipStream_t stream) {
    const float* x     = (const float*)d_in[0];
    const float* gw    = (const float*)d_in[1];
    const float* egu   = (const float*)d_in[2];
    const float* edown = (const float*)d_in[3];
    const float* sgu   = (const float*)d_in[4];
    const float* sdown = (const float*)d_in[5];
    const float* sgate = (const float*)d_in[6];
    float* out = (float*)d_out;
    char* ws = (char*)d_ws;

    const size_t XB_OFF     = 0;
    const size_t WGU_OFF    = XB_OFF     + (size_t)4096*1024*2;
    const size_t WDOWN_OFF  = WGU_OFF    + (size_t)16*2048*1024*2;
    const size_t WSGU_OFF   = WDOWN_OFF  + (size_t)16*1024*1024*2;
    const size_t WSDOWN_OFF = WSGU_OFF   + (size_t)4096*1024*2;
    const size_t HEXP_OFF   = WSDOWN_OFF + (size_t)1024*2048*2;
    const size_t HSH_OFF    = HEXP_OFF   + (size_t)8192*1024*2;
    const size_t OSLOT_OFF  = HSH_OFF    + (size_t)4096*2048*2;
    const size_t TID_OFF    = OSLOT_OFF  + (size_t)8192*1024*4;
    const size_t TW_OFF     = TID_OFF    + 4096*2*4;
    const size_t GATE_OFF   = TW_OFF     + 4096*2*4;
    const size_t TOKL_OFF   = GATE_OFF   + 4096*4;
    const size_t TOKW_OFF   = TOKL_OFF   + 8192*4;
    const size_t SLOT_OFF   = TOKW_OFF   + 8192*4;
    const size_t CNT_OFF    = SLOT_OFF   + 8192*4;
    const size_t OFFS_OFF   = CNT_OFF    + 256;
    const size_t CUR_OFF    = OFFS_OFF   + 256;
    const size_t TMAP_OFF   = CUR_OFF    + 256;
    const size_t NT_OFF     = TMAP_OFF   + 512;

    short* xb      = (short*)(ws + XB_OFF);
    short* wgu_b   = (short*)(ws + WGU_OFF);
    short* wdown_b = (short*)(ws + WDOWN_OFF);
    short* wsgu_b  = (short*)(ws + WSGU_OFF);
    short* wsdn_b  = (short*)(ws + WSDOWN_OFF);
    short* h_exp   = (short*)(ws + HEXP_OFF);
    short* h_sh    = (short*)(ws + HSH_OFF);
    float* oslots  = (float*)(ws + OSLOT_OFF);
    int*   topk_id = (int*)(ws + TID_OFF);
    float* topk_w  = (float*)(ws + TW_OFF);
    float* gate    = (float*)(ws + GATE_OFF);
    int*   tok_l   = (int*)(ws + TOKL_OFF);
    float* tok_w   = (float*)(ws + TOKW_OFF);
    int*   slot_of = (int*)(ws + SLOT_OFF);
    int*   counts  = (int*)(ws + CNT_OFF);
    int*   offsets = (int*)(ws + OFFS_OFF);
    int*   cursor  = (int*)(ws + CUR_OFF);
    int*   tmap    = (int*)(ws + TMAP_OFF);
    int*   ntiles  = (int*)(ws + NT_OFF);

    hipMemsetAsync(counts, 0, 64, stream);

    convert_all_kernel<<<27648, 256, 0, stream>>>(egu, wgu_b, edown, wdown_b,
                                                  sgu, wsgu_b, sdown, wsdn_b);
    router_kernel<<<T_TOKENS / 4, 256, 0, stream>>>(x, gw, sgate, xb, topk_id, topk_w, gate, counts);
    offsets_kernel<<<1, 64, 0, stream>>>(counts, offsets, cursor, tmap, ntiles);
    scatter_kernel<<<T_TOKENS / 256, 256, 0, stream>>>(topk_id, topk_w, cursor, tok_l, tok_w, slot_of);

    gemm1_kernel<<<dim3(MAX_T256 + 16, 16), 512, 0, stream>>>(
        xb, wgu_b, wsgu_b, h_exp, h_sh, tok_l, offsets, counts, tmap, ntiles);

    gemm2_kernel<<<dim3(MAX_T256 + 16, 8), 512, 0, stream>>>(
        h_exp, h_sh, wdown_b, wsdn_b, oslots, out, tok_w, gate, offsets, counts, tmap, ntiles);

    combine_kernel<<<T_TOKENS, 256, 0, stream>>>(out, oslots, slot_of);
}

// Round 5
// 604.791 us; speedup vs baseline: 2.0268x; 1.1461x over previous
//
#include <hip/hip_runtime.h>
#include <hip/hip_bf16.h>

#define T_TOKENS 4096
#define D_MODEL  1024
#define N_EXP    16
#define D_FF     1024
#define D_FF_SH  2048
#define MAX_T256 48   // sum ceil(count_e/256) <= 8192/256 + 16 = 48

typedef __attribute__((ext_vector_type(8))) short short8;
typedef __attribute__((ext_vector_type(4))) float float4v;

__device__ __forceinline__ short f2bf(float f) {
    union { float f; unsigned u; } c; c.f = f;
    unsigned u = c.u + 0x7fffu + ((c.u >> 16) & 1u);
    return (short)(u >> 16);
}

// async global->LDS, 16B per lane; LDS dest = wave-uniform base + lane*16.
__device__ __forceinline__ void gload16(const void* g, void* l) {
    __builtin_amdgcn_global_load_lds(
        (const __attribute__((address_space(1))) void*)g,
        (__attribute__((address_space(3))) void*)l, 16, 0, 0);
}

// ---------------------------------------------------------------- convert (all 4 weights, one dispatch)
__global__ __launch_bounds__(256) void convert_all_kernel(
    const float* __restrict__ s0, short* __restrict__ d0,   // egu   33554432
    const float* __restrict__ s1, short* __restrict__ d1,   // edown 16777216
    const float* __restrict__ s2, short* __restrict__ d2,   // sgu    4194304
    const float* __restrict__ s3, short* __restrict__ d3) { // sdown  2097152
    int c = blockIdx.x * 256 + threadIdx.x;   // chunk of 8 elements
    const float* s; short* d; int off;
    if      (c < 4194304) { s = s0; d = d0; off = c; }
    else if (c < 6291456) { s = s1; d = d1; off = c - 4194304; }
    else if (c < 6815744) { s = s2; d = d2; off = c - 6291456; }
    else                  { s = s3; d = d3; off = c - 6815744; }
    size_t i = (size_t)off * 8;
    float4 a = *(const float4*)(s + i);
    float4 b = *(const float4*)(s + i + 4);
    union { short sh[8]; int4 v; } p;
    p.sh[0] = f2bf(a.x); p.sh[1] = f2bf(a.y); p.sh[2] = f2bf(a.z); p.sh[3] = f2bf(a.w);
    p.sh[4] = f2bf(b.x); p.sh[5] = f2bf(b.y); p.sh[6] = f2bf(b.z); p.sh[7] = f2bf(b.w);
    *(int4*)(d + i) = p.v;
}

// ---------------------------------------------------------------- router (fp32 exact, LDS-staged weights)
// grid 256 x 256 threads. Block handles 16 tokens (4 per wave). gw+sgw staged to LDS (68 KB fp32).
// Each lane: 4 consecutive d's (float4), 4 tokens batched -> 17 independent LDS loads per step.
__global__ __launch_bounds__(256) void router_kernel(
    const float* __restrict__ x, const float* __restrict__ gw, const float* __restrict__ sgw,
    short* __restrict__ xb, int* __restrict__ topk_id, float* __restrict__ topk_w,
    float* __restrict__ gate, int* __restrict__ counts) {
    __shared__ float gwl[17 * 1024];   // 69632 B
    int tid = threadIdx.x;
#pragma unroll
    for (int i = 0; i < 16; i++)
        *(float4*)&gwl[tid * 4 + i * 1024] = *(const float4*)&gw[tid * 4 + i * 1024];
    *(float4*)&gwl[16384 + tid * 4] = *(const float4*)&sgw[tid * 4];
    __syncthreads();

    int wave = tid >> 6, lane = tid & 63;
    int t0 = blockIdx.x * 16 + wave * 4;

    float acc[4][17];
#pragma unroll
    for (int tt = 0; tt < 4; tt++)
#pragma unroll
        for (int e = 0; e < 17; e++) acc[tt][e] = 0.f;

#pragma unroll
    for (int i = 0; i < 4; i++) {
        int d = lane * 4 + i * 256;
        float4 xv[4];
#pragma unroll
        for (int tt = 0; tt < 4; tt++) {
            xv[tt] = *(const float4*)&x[(size_t)(t0 + tt) * D_MODEL + d];
            union { short sh[4]; int2 v; } p;
            p.sh[0] = f2bf(xv[tt].x); p.sh[1] = f2bf(xv[tt].y);
            p.sh[2] = f2bf(xv[tt].z); p.sh[3] = f2bf(xv[tt].w);
            *(int2*)&xb[(size_t)(t0 + tt) * D_MODEL + d] = p.v;
        }
#pragma unroll
        for (int e = 0; e < 17; e++) {
            float4 g = *(const float4*)&gwl[e * 1024 + d];
#pragma unroll
            for (int tt = 0; tt < 4; tt++)
                acc[tt][e] += xv[tt].x * g.x + xv[tt].y * g.y + xv[tt].z * g.z + xv[tt].w * g.w;
        }
    }

#pragma unroll
    for (int tt = 0; tt < 4; tt++)
#pragma unroll
        for (int e = 0; e < 17; e++)
            for (int off = 32; off; off >>= 1) acc[tt][e] += __shfl_xor(acc[tt][e], off);

    if (lane == 0) {
#pragma unroll
        for (int tt = 0; tt < 4; tt++) {
            int t = t0 + tt;
            float v1 = -1e30f, v2 = -1e30f; int i1 = 0, i2 = 0;
#pragma unroll
            for (int e = 0; e < 16; e++) {
                float v = acc[tt][e];
                if (v > v1) { v2 = v1; i2 = i1; v1 = v; i1 = e; }
                else if (v > v2) { v2 = v; i2 = e; }
            }
            float e2 = expf(v2 - v1);
            float s = 1.f + e2;
            topk_id[t * 2] = i1; topk_id[t * 2 + 1] = i2;
            topk_w[t * 2] = 1.f / s; topk_w[t * 2 + 1] = e2 / s;
            gate[t] = 1.f / (1.f + expf(-acc[tt][16]));
            atomicAdd(&counts[i1], 1); atomicAdd(&counts[i2], 1);
        }
    }
}

// ---------------------------------------------------------------- offsets + live 256-row-tile map
__global__ void offsets_kernel(const int* __restrict__ counts, int* __restrict__ offsets,
                               int* __restrict__ cursor, int* __restrict__ tile_map,
                               int* __restrict__ n_tiles) {
    if (threadIdx.x == 0) {
        int off = 0, nt = 0;
        for (int e = 0; e < N_EXP; e++) {
            offsets[e] = off; cursor[e] = off;
            int c = counts[e];
            for (int r = 0; r < c; r += 256) tile_map[nt++] = (e << 16) | (r >> 8);
            off += c;
        }
        n_tiles[0] = nt;
    }
}

__global__ __launch_bounds__(256) void scatter_kernel(
    const int* __restrict__ topk_id, const float* __restrict__ topk_w,
    int* __restrict__ cursor, int* __restrict__ tok_list, float* __restrict__ tok_w,
    int* __restrict__ slot_of) {
    int t = blockIdx.x * 256 + threadIdx.x;
#pragma unroll
    for (int k = 0; k < 2; k++) {
        int e = topk_id[t * 2 + k];
        int pos = atomicAdd(&cursor[e], 1);
        tok_list[pos] = t;
        tok_w[pos] = topk_w[t * 2 + k];
        slot_of[t * 2 + k] = pos;
    }
}

// ---------------------------------------------------------------- GEMM1: 256x128 tile, fused gate+up
// grid (64,16): bx<48 expert tiles (by<8); bx in 48..63 -> shared row-tile, by<16.
// 512 threads = 8 waves, wave-tile 64x64 (dual acc). LDS: 2 x 32KB slices (A16K|Bg8K|Bu8K).
__global__ __launch_bounds__(512, 2) void gemm1_kernel(
    const short* __restrict__ xb,
    const short* __restrict__ Wexp,   // [16][2048][1024]
    const short* __restrict__ Wsh,    // [4096][1024]
    short* __restrict__ Hexp,         // [8192][1024]
    short* __restrict__ Hsh,          // [4096][2048]
    const int* __restrict__ tok_list,
    const int* __restrict__ offsets, const int* __restrict__ counts,
    const int* __restrict__ tile_map, const int* __restrict__ n_tiles) {
    int bx = blockIdx.x, by = blockIdx.y;
    int count, row0, dff;
    const int* idx = nullptr;
    const short* Wg; short* Hout;
    if (bx < MAX_T256) {
        if (by >= 8 || bx >= n_tiles[0]) return;
        int tm = tile_map[bx];
        int e = tm >> 16; row0 = (tm & 0xffff) << 8;
        count = counts[e];
        int base = offsets[e];
        idx = tok_list + base;
        Wg = Wexp + (size_t)e * 2 * D_FF * D_MODEL;
        Hout = Hexp + (size_t)base * D_FF;
        dff = D_FF;
    } else {
        row0 = (bx - MAX_T256) * 256; count = T_TOKENS;
        Wg = Wsh; Hout = Hsh; dff = D_FF_SH;
    }
    int col0 = by * 128;
    const short* Wu = Wg + (size_t)dff * D_MODEL;

    __shared__ char lds[65536];

    int t = threadIdx.x;
    int wave = t >> 6, lane = t & 63;
    int wm = (wave & 3) * 64, wn = (wave >> 2) * 64;
    int fr = lane & 15, fk2 = (lane >> 4) * 16;   // byte offset of 8-short chunk

    float4v accg[4][4], accu[4][4];
#pragma unroll
    for (int i = 0; i < 4; i++)
#pragma unroll
        for (int j = 0; j < 4; j++) { accg[i][j] = (float4v)0.f; accu[i][j] = (float4v)0.f; }

    // staging: thread t handles row (t>>2) for each region, 16B chunk (t&3)
    int rA = t >> 2;              // 0..127
    int cq = (t & 3) * 8;         // shorts
    int r0c = min(row0 + rA, count - 1);
    int r1c = min(row0 + rA + 128, count - 1);
    int g0 = idx ? idx[r0c] : r0c;
    int g1 = idx ? idx[r1c] : r1c;
    const short* aP0 = xb + (size_t)g0 * D_MODEL + cq;
    const short* aP1 = xb + (size_t)g1 * D_MODEL + cq;
    const short* bgP = Wg + (size_t)(col0 + rA) * D_MODEL + cq;
    const short* buP = Wu + (size_t)(col0 + rA) * D_MODEL + cq;
    int lo = t * 16;              // 0..8191

    // prologue: issue slice 0 into buf 0
    gload16(aP0, lds + lo);
    gload16(aP1, lds + 8192 + lo);
    gload16(bgP, lds + 16384 + lo);
    gload16(buP, lds + 24576 + lo);

    const int NK = D_MODEL / 32;  // 32 slices
    for (int k = 0; k < NK; k++) {
        __syncthreads();          // drains slice-k DMAs (overlapped by compute(k-1))
        if (k + 1 < NK) {
            int s = ((k + 1) & 1) * 32768;
            int off = (k + 1) * 32;   // shorts
            gload16(aP0 + off, lds + s + lo);
            gload16(aP1 + off, lds + s + 8192 + lo);
            gload16(bgP + off, lds + s + 16384 + lo);
            gload16(buP + off, lds + s + 24576 + lo);
        }
        int sb = (k & 1) * 32768;
        short8 af[4], bgf[4], buf[4];
#pragma unroll
        for (int i = 0; i < 4; i++)
            af[i] = *(const short8*)(lds + sb + (wm + i * 16 + fr) * 64 + fk2);
#pragma unroll
        for (int j = 0; j < 4; j++) {
            bgf[j] = *(const short8*)(lds + sb + 16384 + (wn + j * 16 + fr) * 64 + fk2);
            buf[j] = *(const short8*)(lds + sb + 24576 + (wn + j * 16 + fr) * 64 + fk2);
        }
#pragma unroll
        for (int i = 0; i < 4; i++)
#pragma unroll
            for (int j = 0; j < 4; j++) {
                accg[i][j] = __builtin_amdgcn_mfma_f32_16x16x32_bf16(af[i], bgf[j], accg[i][j], 0, 0, 0);
                accu[i][j] = __builtin_amdgcn_mfma_f32_16x16x32_bf16(af[i], buf[j], accu[i][j], 0, 0, 0);
            }
    }

    int erow = (lane >> 4) * 4;
    int ecol = lane & 15;
#pragma unroll
    for (int i = 0; i < 4; i++)
#pragma unroll
        for (int j = 0; j < 4; j++)
#pragma unroll
            for (int r = 0; r < 4; r++) {
                int row = wm + i * 16 + erow + r;
                if (row0 + row < count) {
                    float g = accg[i][j][r], u = accu[i][j][r];
                    float h = g / (1.f + expf(-g)) * u;
                    Hout[(size_t)(row0 + row) * dff + col0 + wn + j * 16 + ecol] = f2bf(h);
                }
            }
}

// ---------------------------------------------------------------- GEMM2: 256x128 tile
// grid (64,8). Expert: pre-weighted plain stores to oslots. Shared (K=2048): gated stores to out.
__global__ __launch_bounds__(512, 2) void gemm2_kernel(
    const short* __restrict__ Hexp, const short* __restrict__ Hsh,
    const short* __restrict__ Wdexp,  // [16][1024][1024]
    const short* __restrict__ Wdsh,   // [1024][2048]
    float* __restrict__ oslots,       // [8192][1024]
    float* __restrict__ out,          // [4096][1024]
    const float* __restrict__ tok_w, const float* __restrict__ gate,
    const int* __restrict__ offsets, const int* __restrict__ counts,
    const int* __restrict__ tile_map, const int* __restrict__ n_tiles) {
    int bx = blockIdx.x, by = blockIdx.y;
    int count, row0, K, base;
    const short* Ab; const short* B;
    bool shared_part;
    if (bx < MAX_T256) {
        if (bx >= n_tiles[0]) return;
        int tm = tile_map[bx];
        int e = tm >> 16; row0 = (tm & 0xffff) << 8;
        count = counts[e]; base = offsets[e];
        Ab = Hexp + (size_t)base * D_FF; K = D_FF;
        B = Wdexp + (size_t)e * D_MODEL * D_FF;
        shared_part = false;
    } else {
        row0 = (bx - MAX_T256) * 256; count = T_TOKENS; base = 0;
        Ab = Hsh; K = D_FF_SH; B = Wdsh; shared_part = true;
    }
    int col0 = by * 128;

    __shared__ char lds[49152];   // 2 x 24KB slices (A16K|B8K)

    int t = threadIdx.x;
    int wave = t >> 6, lane = t & 63;
    int wm = (wave & 3) * 64, wn = (wave >> 2) * 64;
    int fr = lane & 15, fk2 = (lane >> 4) * 16;

    float4v acc[4][4];
#pragma unroll
    for (int i = 0; i < 4; i++)
#pragma unroll
        for (int j = 0; j < 4; j++) acc[i][j] = (float4v)0.f;

    int rA = t >> 2;
    int cq = (t & 3) * 8;
    int r0c = min(row0 + rA, count - 1);
    int r1c = min(row0 + rA + 128, count - 1);
    const short* aP0 = Ab + (size_t)r0c * K + cq;
    const short* aP1 = Ab + (size_t)r1c * K + cq;
    const short* bP  = B + (size_t)(col0 + rA) * K + cq;
    int lo = t * 16;

    gload16(aP0, lds + lo);
    gload16(aP1, lds + 8192 + lo);
    gload16(bP,  lds + 16384 + lo);

    const int NK = K / 32;        // 32 or 64
    for (int k = 0; k < NK; k++) {
        __syncthreads();
        if (k + 1 < NK) {
            int s = ((k + 1) & 1) * 24576;
            int off = (k + 1) * 32;
            gload16(aP0 + off, lds + s + lo);
            gload16(aP1 + off, lds + s + 8192 + lo);
            gload16(bP + off,  lds + s + 16384 + lo);
        }
        int sb = (k & 1) * 24576;
        short8 af[4], bf[4];
#pragma unroll
        for (int i = 0; i < 4; i++)
            af[i] = *(const short8*)(lds + sb + (wm + i * 16 + fr) * 64 + fk2);
#pragma unroll
        for (int j = 0; j < 4; j++)
            bf[j] = *(const short8*)(lds + sb + 16384 + (wn + j * 16 + fr) * 64 + fk2);
#pragma unroll
        for (int i = 0; i < 4; i++)
#pragma unroll
            for (int j = 0; j < 4; j++)
                acc[i][j] = __builtin_amdgcn_mfma_f32_16x16x32_bf16(af[i], bf[j], acc[i][j], 0, 0, 0);
    }

    int erow = (lane >> 4) * 4;
    int ecol = lane & 15;
#pragma unroll
    for (int i = 0; i < 4; i++)
#pragma unroll
        for (int j = 0; j < 4; j++)
#pragma unroll
            for (int r = 0; r < 4; r++) {
                int row = wm + i * 16 + erow + r;
                if (row0 + row < count) {
                    float v = acc[i][j][r];
                    int col = col0 + wn + j * 16 + ecol;
                    if (!shared_part) {
                        int slot = base + row0 + row;
                        oslots[(size_t)slot * D_MODEL + col] = tok_w[slot] * v;
                    } else {
                        out[(size_t)(row0 + row) * D_MODEL + col] = gate[row0 + row] * v;
                    }
                }
            }
}

// ---------------------------------------------------------------- combine: out[t] += oslots[sA] + oslots[sB]
__global__ __launch_bounds__(256) void combine_kernel(
    float* __restrict__ out, const float* __restrict__ oslots,
    const int* __restrict__ slot_of) {
    int t = blockIdx.x;
    int sA = slot_of[t * 2], sB = slot_of[t * 2 + 1];
    int d = threadIdx.x * 4;
    float4 o = *(float4*)&out[(size_t)t * D_MODEL + d];
    float4 a = *(const float4*)&oslots[(size_t)sA * D_MODEL + d];
    float4 b = *(const float4*)&oslots[(size_t)sB * D_MODEL + d];
    o.x += a.x + b.x; o.y += a.y + b.y; o.z += a.z + b.z; o.w += a.w + b.w;
    *(float4*)&out[(size_t)t * D_MODEL + d] = o;
}

// ---------------------------------------------------------------- host
extern "C" void kernel_launch(void* const* d_in, const int* in_sizes, int n_in,
                              void* d_out, int out_size, void* d_ws, size_t ws_size,
                              hipStream_t stream) {
    const float* x     = (const float*)d_in[0];
    const float* gw    = (const float*)d_in[1];
    const float* egu   = (const float*)d_in[2];
    const float* edown = (const float*)d_in[3];
    const float* sgu   = (const float*)d_in[4];
    const float* sdown = (const float*)d_in[5];
    const float* sgate = (const float*)d_in[6];
    float* out = (float*)d_out;
    char* ws = (char*)d_ws;

    const size_t XB_OFF     = 0;
    const size_t WGU_OFF    = XB_OFF     + (size_t)4096*1024*2;
    const size_t WDOWN_OFF  = WGU_OFF    + (size_t)16*2048*1024*2;
    const size_t WSGU_OFF   = WDOWN_OFF  + (size_t)16*1024*1024*2;
    const size_t WSDOWN_OFF = WSGU_OFF   + (size_t)4096*1024*2;
    const size_t HEXP_OFF   = WSDOWN_OFF + (size_t)1024*2048*2;
    const size_t HSH_OFF    = HEXP_OFF   + (size_t)8192*1024*2;
    const size_t OSLOT_OFF  = HSH_OFF    + (size_t)4096*2048*2;
    const size_t TID_OFF    = OSLOT_OFF  + (size_t)8192*1024*4;
    const size_t TW_OFF     = TID_OFF    + 4096*2*4;
    const size_t GATE_OFF   = TW_OFF     + 4096*2*4;
    const size_t TOKL_OFF   = GATE_OFF   + 4096*4;
    const size_t TOKW_OFF   = TOKL_OFF   + 8192*4;
    const size_t SLOT_OFF   = TOKW_OFF   + 8192*4;
    const size_t CNT_OFF    = SLOT_OFF   + 8192*4;
    const size_t OFFS_OFF   = CNT_OFF    + 256;
    const size_t CUR_OFF    = OFFS_OFF   + 256;
    const size_t TMAP_OFF   = CUR_OFF    + 256;
    const size_t NT_OFF     = TMAP_OFF   + 512;

    short* xb      = (short*)(ws + XB_OFF);
    short* wgu_b   = (short*)(ws + WGU_OFF);
    short* wdown_b = (short*)(ws + WDOWN_OFF);
    short* wsgu_b  = (short*)(ws + WSGU_OFF);
    short* wsdn_b  = (short*)(ws + WSDOWN_OFF);
    short* h_exp   = (short*)(ws + HEXP_OFF);
    short* h_sh    = (short*)(ws + HSH_OFF);
    float* oslots  = (float*)(ws + OSLOT_OFF);
    int*   topk_id = (int*)(ws + TID_OFF);
    float* topk_w  = (float*)(ws + TW_OFF);
    float* gate    = (float*)(ws + GATE_OFF);
    int*   tok_l   = (int*)(ws + TOKL_OFF);
    float* tok_w   = (float*)(ws + TOKW_OFF);
    int*   slot_of = (int*)(ws + SLOT_OFF);
    int*   counts  = (int*)(ws + CNT_OFF);
    int*   offsets = (int*)(ws + OFFS_OFF);
    int*   cursor  = (int*)(ws + CUR_OFF);
    int*   tmap    = (int*)(ws + TMAP_OFF);
    int*   ntiles  = (int*)(ws + NT_OFF);

    hipMemsetAsync(counts, 0, 64, stream);

    convert_all_kernel<<<27648, 256, 0, stream>>>(egu, wgu_b, edown, wdown_b,
                                                  sgu, wsgu_b, sdown, wsdn_b);
    router_kernel<<<256, 256, 0, stream>>>(x, gw, sgate, xb, topk_id, topk_w, gate, counts);
    offsets_kernel<<<1, 64, 0, stream>>>(counts, offsets, cursor, tmap, ntiles);
    scatter_kernel<<<T_TOKENS / 256, 256, 0, stream>>>(topk_id, topk_w, cursor, tok_l, tok_w, slot_of);

    gemm1_kernel<<<dim3(MAX_T256 + 16, 16), 512, 0, stream>>>(
        xb, wgu_b, wsgu_b, h_exp, h_sh, tok_l, offsets, counts, tmap, ntiles);

    gemm2_kernel<<<dim3(MAX_T256 + 16, 8), 512, 0, stream>>>(
        h_exp, h_sh, wdown_b, wsdn_b, oslots, out, tok_w, gate, offsets, counts, tmap, ntiles);

    combine_kernel<<<T_TOKENS, 256, 0, stream>>>(out, oslots, slot_of);
}